// Round 9
// baseline (858.639 us; speedup 1.0000x reference)
//
#include <hip/hip_runtime.h>
#include <cmath>

namespace {

constexpr int L = 8, H = 1536, W = 1536, HW = H * W, C = 12;
constexpr int TWB = 128, TH = 16;          // block output tile 128x16
constexpr int LH = TH + 10;                // 26 tile rows
constexpr int LPAD = 8;                    // left halo padded to 8 for 16B alignment
constexpr int LCOLS = 148;                 // 36 float4 data slots (144) + 4 pad
// tile col c <-> global x = bx*128 - 8 + c

// nonzero-tap extents of the 11x11 disc (dist<=5)
__device__ __host__ constexpr int XLO[11]  = {5, 2, 1, 1, 1, 0, 1, 1, 1, 2, 5};
__device__ __host__ constexpr int XHI[11]  = {5, 8, 9, 9, 9,10, 9, 9, 9, 8, 5};
__device__ __host__ constexpr int WOFF[11] = {0, 1, 8,17,26,35,46,55,64,73,80}; // 81 total

// fixed topology from the reference (_PAIRS)
__device__ constexpr int CSRC[C] = {0,1,2,3,4,5,6,0,2,4,7,3};
__device__ constexpr int CDST[C] = {1,2,3,4,5,6,7,2,4,6,0,5};

struct Weights { float w[81]; };

// ---------------- fast kernel ----------------
// (256, 6): cap ~= 512/6 ~= 85 VGPR, natural demand is 84 -> no spill expected.
// Canary: WRITE_SIZE must stay ~74 MB; if it balloons, the pin spilled.
__global__ __launch_bounds__(256, 6)
void snn_fast(const float* __restrict__ ext,
              const float* __restrict__ spk,
              const float* __restrict__ mem,
              const float* __restrict__ iw,
              const int*   __restrict__ refr,
              float* __restrict__ out,
              unsigned*    wslist,          // [0]=count, [1..cap]=gidx list
              unsigned     cap,
              const Weights wt)
{
    __shared__ float tile[LH][LCOLS];

    const int tx = threadIdx.x;          // 0..31
    const int ty = threadIdx.y;          // 0..7
    const int tid = ty * 32 + tx;
    const int bx = blockIdx.x, by = blockIdx.y, l = blockIdx.z;

    // ---- stage spike tile: aligned float4 path, edge fallback ----
    const int gx0 = bx * TWB - LPAD;     // global x of tile col 0 (16B aligned)
    const int gy0 = by * TH - 5;
    const float* sp_l = spk + l * HW;
    for (int idx = tid; idx < LH * 36; idx += 256) {
        const int r    = idx / 36;
        const int slot = idx - r * 36;
        const int gy = gy0 + r;
        const int gx = gx0 + 4 * slot;
        float4 v = make_float4(0.f, 0.f, 0.f, 0.f);
        if ((unsigned)gy < (unsigned)H) {
            const float* src = sp_l + gy * W;
            if (gx >= 0 && gx + 3 < W) {
                v = *(const float4*)(src + gx);       // 16B aligned
            } else {
                float t0 = 0.f, t1 = 0.f, t2 = 0.f, t3 = 0.f;
                if ((unsigned)(gx + 0) < (unsigned)W) t0 = src[gx + 0];
                if ((unsigned)(gx + 1) < (unsigned)W) t1 = src[gx + 1];
                if ((unsigned)(gx + 2) < (unsigned)W) t2 = src[gx + 2];
                if ((unsigned)(gx + 3) < (unsigned)W) t3 = src[gx + 3];
                v = make_float4(t0, t1, t2, t3);
            }
        }
        *(float4*)&tile[r][4 * slot] = v;             // 16B aligned
    }
    __syncthreads();

    // ---- conv: 4 cols x 2 rows per thread, b128 window loads ----
    float acc[2][4] = {{0.f,0.f,0.f,0.f},{0.f,0.f,0.f,0.f}};
    #pragma unroll
    for (int j = 0; j < 12; ++j) {                    // tile row = ty*2 + j
        const float* row = &tile[ty * 2 + j][0];
        alignas(16) float win[20];
        *(float4*)&win[0]  = *(const float4*)&row[4 * tx + 0];
        *(float4*)&win[4]  = *(const float4*)&row[4 * tx + 4];
        *(float4*)&win[8]  = *(const float4*)&row[4 * tx + 8];
        *(float4*)&win[12] = *(const float4*)&row[4 * tx + 12];
        win[16] = row[4 * tx + 16];
        #pragma unroll
        for (int k = 0; k < 2; ++k) {
            const int dy = j - k;
            if (dy < 0 || dy > 10) continue;          // compile-time pruned
            #pragma unroll
            for (int dx = XLO[dy]; dx <= XHI[dy]; ++dx) {
                const float wv = wt.w[WOFF[dy] + dx - XLO[dy]];  // SGPR
                #pragma unroll
                for (int c = 0; c < 4; ++c)
                    acc[k][c] += wv * win[3 + c + dx];  // window base offset 3
            }
        }
    }

    // ---- tail: axonal + LIF + threshold, all float4, per output row ----
    const int ox = bx * TWB + 4 * tx;
    #pragma unroll
    for (int k = 0; k < 2; ++k) {
        const int oy   = by * TH + ty * 2 + k;
        const int pidx = oy * W + ox;
        const int gidx = l * HW + pidx;

        const int4   rf4 = *(const int4*)  (refr + gidx);
        const float4 e4  = *(const float4*)(ext  + gidx);
        const float4 m4  = *(const float4*)(mem  + gidx);

        float ax0 = 0.f, ax1 = 0.f, ax2 = 0.f, ax3 = 0.f;
        #pragma unroll
        for (int c = 0; c < C; ++c) {
            if (CDST[c] != l) continue;               // block-uniform
            const float4 s4 = *(const float4*)(spk + CSRC[c] * HW + pidx);
            const float4 w4 = *(const float4*)(iw  + c       * HW + pidx);
            ax0 += s4.x * w4.x; ax1 += s4.y * w4.y;
            ax2 += s4.z * w4.z; ax3 += s4.w * w4.w;
        }
        const float ee[4] = {e4.x, e4.y, e4.z, e4.w};
        const float mm[4] = {m4.x, m4.y, m4.z, m4.w};
        const int   rr[4] = {rf4.x, rf4.y, rf4.z, rf4.w};
        const float aa[4] = {ax0, ax1, ax2, ax3};
        float res[4];
        #pragma unroll
        for (int c = 0; c < 4; ++c) {
            const float v = 0.9f * mm[c] + (ee[c] + acc[k][c] + aa[c]);
            res[c] = (rr[c] == 0 && v > 0.f) ? 1.f : 0.f;
            if (rr[c] == 0 && __builtin_expect(fabsf(v) < 1e-3f, 0)) {
                const unsigned idx = atomicAdd(wslist, 1u);
                if (idx < cap) wslist[1 + idx] = (unsigned)(gidx + c);
            }
        }
        *(float4*)(out + gidx) = make_float4(res[0], res[1], res[2], res[3]);
    }
}

// ---------------- fixup kernel: exact f64 recompute of flagged pixels ----------------
__global__ __launch_bounds__(256)
void snn_fixup(const float* __restrict__ ext,
               const float* __restrict__ spk,
               const float* __restrict__ mem,
               const float* __restrict__ iw,
               const float* __restrict__ lk,
               float* __restrict__ out,
               const unsigned* __restrict__ wslist,
               unsigned cap)
{
    const unsigned n = min(wslist[0], cap);
    for (unsigned i = blockIdx.x * blockDim.x + threadIdx.x; i < n;
         i += gridDim.x * blockDim.x) {
        const unsigned gidx = wslist[1 + i];
        const int l    = gidx / HW;
        const int pidx = gidx - l * HW;
        const int oy   = pidx / W;
        const int ox   = pidx - oy * W;

        const float* sp = spk + l * HW;
        double conv = 0.0;
        for (int dy = 0; dy < 11; ++dy) {
            const int yy = oy + dy - 5;
            if ((unsigned)yy >= (unsigned)H) continue;
            for (int dx = 0; dx < 11; ++dx) {
                const int xx = ox + dx - 5;
                if ((unsigned)xx >= (unsigned)W) continue;
                conv += (double)lk[dy * 11 + dx] * (double)sp[yy * W + xx];
            }
        }
        double ax = 0.0;
        #pragma unroll
        for (int c = 0; c < C; ++c)
            if (CDST[c] == l)
                ax += (double)spk[CSRC[c] * HW + pidx] * (double)iw[c * HW + pidx];
        const double tot = ((double)ext[gidx] + conv) + ax;
        const double vd  = 0.9 * (double)mem[gidx] + tot;
        out[gidx] = (vd > 0.0) ? 1.f : 0.f;
    }
}

} // namespace

extern "C" void kernel_launch(void* const* d_in, const int* in_sizes, int n_in,
                              void* d_out, int out_size, void* d_ws, size_t ws_size,
                              hipStream_t stream) {
    const float* ext  = (const float*)d_in[0];
    const float* spk  = (const float*)d_in[1];
    const float* mem  = (const float*)d_in[2];
    const float* iw   = (const float*)d_in[3];
    const float* lk   = (const float*)d_in[4];
    const int*   refr = (const int*)  d_in[5];
    float* o = (float*)d_out;

    // host-side f64 weight computation, mirroring numpy
    Weights wt;
    for (int dy = 0; dy < 11; ++dy) {
        for (int dx = XLO[dy]; dx <= XHI[dy]; ++dx) {
            const double ddy = dy - 5, ddx = dx - 5;
            const double dist = std::sqrt(ddy * ddy + ddx * ddx);
            double w = std::exp(-dist / 2.0);
            if (dist > 5.0) w = 0.0;
            if (dy == 5 && dx == 5) w = 0.0;
            wt.w[WOFF[dy] + dx - XLO[dy]] = (float)w;
        }
    }

    dim3 grid(W / TWB, H / TH, L);   // (12, 96, 8)
    dim3 block(32, 8, 1);

    unsigned* wsl = (unsigned*)d_ws;
    size_t cap64 = ws_size / 4 - 1;
    const unsigned cap = (unsigned)(cap64 > 0x7FFFFFFFu ? 0x7FFFFFFFu : cap64);
    hipMemsetAsync(d_ws, 0, 4, stream);   // zero the counter (graph-safe)
    hipLaunchKernelGGL(snn_fast, grid, block, 0, stream,
                       ext, spk, mem, iw, refr, o, wsl, cap, wt);
    hipLaunchKernelGGL(snn_fixup, dim3(64), dim3(256), 0, stream,
                       ext, spk, mem, iw, lk, o, wsl, cap);
}

// Round 10
// 222.677 us; speedup vs baseline: 3.8560x; 3.8560x over previous
//
#include <hip/hip_runtime.h>
#include <cmath>

namespace {

constexpr int L = 8, H = 1536, W = 1536, HW = H * W, C = 12;
constexpr int TWB = 128, TH = 16;          // block output tile 128x16

// nonzero-tap extents of the 11x11 disc (dist<=5)
__device__ __host__ constexpr int XLO[11]  = {5, 2, 1, 1, 1, 0, 1, 1, 1, 2, 5};
__device__ __host__ constexpr int XHI[11]  = {5, 8, 9, 9, 9,10, 9, 9, 9, 8, 5};
__device__ __host__ constexpr int WOFF[11] = {0, 1, 8,17,26,35,46,55,64,73,80}; // 81 total

// fixed topology from the reference (_PAIRS)
__device__ constexpr int CSRC[C] = {0,1,2,3,4,5,6,0,2,4,7,3};
__device__ constexpr int CDST[C] = {1,2,3,4,5,6,7,2,4,6,0,5};

struct Weights { float w[81]; };

// Conv body: 4 cols x 2 rows per thread, windows loaded straight from global
// (L1/L2-resident; no LDS, no barrier). GUARD=true only for edge blocks.
template<bool GUARD>
__device__ __forceinline__ void conv_rows(const float* __restrict__ sp_l,
                                          int gy0r, int xbase,
                                          float acc[2][4], const Weights& wt)
{
    #pragma unroll
    for (int j = 0; j < 12; ++j) {                 // window row gy0r + j
        const int gy = gy0r + j;
        const float* rp = sp_l + gy * W + xbase;
        alignas(16) float win[20];
        if (GUARD) {
            const bool rowok = ((unsigned)gy < (unsigned)H);
            #pragma unroll
            for (int s = 0; s < 4; ++s) {
                const int gx = xbase + 4 * s;       // 4-aligned: float4 all-in or all-out
                float4 v = make_float4(0.f, 0.f, 0.f, 0.f);
                if (rowok && gx >= 0 && gx < W)
                    v = *(const float4*)(rp + 4 * s);
                *(float4*)&win[4 * s] = v;
            }
            const int gxs = xbase + 16;
            win[16] = (rowok && gxs >= 0 && gxs < W) ? rp[16] : 0.f;
        } else {
            *(float4*)&win[0]  = *(const float4*)(rp + 0);
            *(float4*)&win[4]  = *(const float4*)(rp + 4);
            *(float4*)&win[8]  = *(const float4*)(rp + 8);
            *(float4*)&win[12] = *(const float4*)(rp + 12);
            win[16] = rp[16];
        }
        #pragma unroll
        for (int k = 0; k < 2; ++k) {
            const int dy = j - k;
            if (dy < 0 || dy > 10) continue;        // compile-time pruned
            #pragma unroll
            for (int dx = XLO[dy]; dx <= XHI[dy]; ++dx) {
                const float wv = wt.w[WOFF[dy] + dx - XLO[dy]];  // SGPR
                #pragma unroll
                for (int c = 0; c < 4; ++c)
                    acc[k][c] += wv * win[3 + c + dx];
            }
        }
    }
}

// ---------------- fast kernel (no LDS, no barrier) ----------------
__global__ __launch_bounds__(256)   // NO min-waves pin (rounds 2/6/9 lesson)
void snn_fast(const float* __restrict__ ext,
              const float* __restrict__ spk,
              const float* __restrict__ mem,
              const float* __restrict__ iw,
              const int*   __restrict__ refr,
              float* __restrict__ out,
              unsigned*    wslist,          // [0]=count, [1..cap]=gidx list
              unsigned     cap,
              const Weights wt)
{
    const int tx = threadIdx.x;          // 0..31
    const int ty = threadIdx.y;          // 0..7
    const int bx = blockIdx.x, by = blockIdx.y, l = blockIdx.z;

    const int ox    = bx * TWB + 4 * tx;
    const int oy0   = by * TH + ty * 2;
    const int xbase = ox - 8;            // window col 0 (4-aligned)
    const int gy0r  = oy0 - 5;           // first window row
    const float* sp_l = spk + l * HW;

    float acc[2][4] = {{0.f,0.f,0.f,0.f},{0.f,0.f,0.f,0.f}};
    const bool interior = (bx >= 1) & (bx <= 10) & (by >= 1) & (by <= 94);
    if (interior) conv_rows<false>(sp_l, gy0r, xbase, acc, wt);
    else          conv_rows<true >(sp_l, gy0r, xbase, acc, wt);

    // ---- tail: axonal + LIF + threshold, all float4, per output row ----
    #pragma unroll
    for (int k = 0; k < 2; ++k) {
        const int oy   = oy0 + k;
        const int pidx = oy * W + ox;
        const int gidx = l * HW + pidx;

        const int4   rf4 = *(const int4*)  (refr + gidx);
        const float4 e4  = *(const float4*)(ext  + gidx);
        const float4 m4  = *(const float4*)(mem  + gidx);

        float ax0 = 0.f, ax1 = 0.f, ax2 = 0.f, ax3 = 0.f;
        #pragma unroll
        for (int c = 0; c < C; ++c) {
            if (CDST[c] != l) continue;               // block-uniform
            const float4 s4 = *(const float4*)(spk + CSRC[c] * HW + pidx);
            const float4 w4 = *(const float4*)(iw  + c       * HW + pidx);
            ax0 += s4.x * w4.x; ax1 += s4.y * w4.y;
            ax2 += s4.z * w4.z; ax3 += s4.w * w4.w;
        }
        const float ee[4] = {e4.x, e4.y, e4.z, e4.w};
        const float mm[4] = {m4.x, m4.y, m4.z, m4.w};
        const int   rr[4] = {rf4.x, rf4.y, rf4.z, rf4.w};
        const float aa[4] = {ax0, ax1, ax2, ax3};
        float res[4];
        #pragma unroll
        for (int c = 0; c < 4; ++c) {
            const float v = 0.9f * mm[c] + (ee[c] + acc[k][c] + aa[c]);
            res[c] = (rr[c] == 0 && v > 0.f) ? 1.f : 0.f;
            if (rr[c] == 0 && __builtin_expect(fabsf(v) < 1e-3f, 0)) {
                const unsigned idx = atomicAdd(wslist, 1u);
                if (idx < cap) wslist[1 + idx] = (unsigned)(gidx + c);
            }
        }
        *(float4*)(out + gidx) = make_float4(res[0], res[1], res[2], res[3]);
    }
}

// ---------------- fixup kernel: exact f64 recompute of flagged pixels ----------------
__global__ __launch_bounds__(256)
void snn_fixup(const float* __restrict__ ext,
               const float* __restrict__ spk,
               const float* __restrict__ mem,
               const float* __restrict__ iw,
               const float* __restrict__ lk,
               float* __restrict__ out,
               const unsigned* __restrict__ wslist,
               unsigned cap)
{
    const unsigned n = min(wslist[0], cap);
    for (unsigned i = blockIdx.x * blockDim.x + threadIdx.x; i < n;
         i += gridDim.x * blockDim.x) {
        const unsigned gidx = wslist[1 + i];
        const int l    = gidx / HW;
        const int pidx = gidx - l * HW;
        const int oy   = pidx / W;
        const int ox   = pidx - oy * W;

        const float* sp = spk + l * HW;
        double conv = 0.0;
        for (int dy = 0; dy < 11; ++dy) {
            const int yy = oy + dy - 5;
            if ((unsigned)yy >= (unsigned)H) continue;
            for (int dx = 0; dx < 11; ++dx) {
                const int xx = ox + dx - 5;
                if ((unsigned)xx >= (unsigned)W) continue;
                conv += (double)lk[dy * 11 + dx] * (double)sp[yy * W + xx];
            }
        }
        double ax = 0.0;
        #pragma unroll
        for (int c = 0; c < C; ++c)
            if (CDST[c] == l)
                ax += (double)spk[CSRC[c] * HW + pidx] * (double)iw[c * HW + pidx];
        const double tot = ((double)ext[gidx] + conv) + ax;
        const double vd  = 0.9 * (double)mem[gidx] + tot;
        out[gidx] = (vd > 0.0) ? 1.f : 0.f;
    }
}

} // namespace

extern "C" void kernel_launch(void* const* d_in, const int* in_sizes, int n_in,
                              void* d_out, int out_size, void* d_ws, size_t ws_size,
                              hipStream_t stream) {
    const float* ext  = (const float*)d_in[0];
    const float* spk  = (const float*)d_in[1];
    const float* mem  = (const float*)d_in[2];
    const float* iw   = (const float*)d_in[3];
    const float* lk   = (const float*)d_in[4];
    const int*   refr = (const int*)  d_in[5];
    float* o = (float*)d_out;

    // host-side f64 weight computation, mirroring numpy
    Weights wt;
    for (int dy = 0; dy < 11; ++dy) {
        for (int dx = XLO[dy]; dx <= XHI[dy]; ++dx) {
            const double ddy = dy - 5, ddx = dx - 5;
            const double dist = std::sqrt(ddy * ddy + ddx * ddx);
            double w = std::exp(-dist / 2.0);
            if (dist > 5.0) w = 0.0;
            if (dy == 5 && dx == 5) w = 0.0;
            wt.w[WOFF[dy] + dx - XLO[dy]] = (float)w;
        }
    }

    dim3 grid(W / TWB, H / TH, L);   // (12, 96, 8)
    dim3 block(32, 8, 1);

    unsigned* wsl = (unsigned*)d_ws;
    size_t cap64 = ws_size / 4 - 1;
    const unsigned cap = (unsigned)(cap64 > 0x7FFFFFFFu ? 0x7FFFFFFFu : cap64);
    hipMemsetAsync(d_ws, 0, 4, stream);   // zero the counter (graph-safe)
    hipLaunchKernelGGL(snn_fast, grid, block, 0, stream,
                       ext, spk, mem, iw, refr, o, wsl, cap, wt);
    hipLaunchKernelGGL(snn_fixup, dim3(64), dim3(256), 0, stream,
                       ext, spk, mem, iw, lk, o, wsl, cap);
}

// Round 11
// 193.608 us; speedup vs baseline: 4.4349x; 1.1501x over previous
//
#include <hip/hip_runtime.h>
#include <cmath>

namespace {

constexpr int L = 8, H = 1536, W = 1536, HW = H * W, C = 12;
constexpr int TWB = 128, TH = 8;           // block output tile 128x8, 128 threads
constexpr int LH = TH + 10;                // 18 tile rows
constexpr int LPAD = 8;                    // left halo padded to 8 for 16B alignment
constexpr int LCOLS = 148;                 // 36 float4 data slots (144) + 4 pad
constexpr int NSLOT = 36;
constexpr int NSTG  = LH * NSLOT;          // 648 staging float4s per block

// nonzero-tap extents of the 11x11 disc (dist<=5)
__device__ __host__ constexpr int XLO[11]  = {5, 2, 1, 1, 1, 0, 1, 1, 1, 2, 5};
__device__ __host__ constexpr int XHI[11]  = {5, 8, 9, 9, 9,10, 9, 9, 9, 8, 5};
__device__ __host__ constexpr int WOFF[11] = {0, 1, 8,17,26,35,46,55,64,73,80}; // 81 total

// fixed topology from the reference (_PAIRS)
__device__ constexpr int CSRC[C] = {0,1,2,3,4,5,6,0,2,4,7,3};
__device__ constexpr int CDST[C] = {1,2,3,4,5,6,7,2,4,6,0,5};

struct Weights { float w[81]; };

// ---------------- fast kernel: 2-wave blocks for cross-block overlap ----------------
__global__ __launch_bounds__(128)   // NO min-waves pin (rounds 2/6/9 lesson)
void snn_fast(const float* __restrict__ ext,
              const float* __restrict__ spk,
              const float* __restrict__ mem,
              const float* __restrict__ iw,
              const int*   __restrict__ refr,
              float* __restrict__ out,
              unsigned*    wslist,          // [0]=count, [1..cap]=gidx list
              unsigned     cap,
              const Weights wt)
{
    __shared__ float tile[LH][LCOLS];

    const int tx = threadIdx.x;          // 0..31
    const int ty = threadIdx.y;          // 0..3
    const int tid = ty * 32 + tx;
    const int bx = blockIdx.x, by = blockIdx.y, l = blockIdx.z;

    // ---- stage spike tile: aligned float4 path, edge fallback ----
    const int gx0 = bx * TWB - LPAD;     // global x of tile col 0 (16B aligned)
    const int gy0 = by * TH - 5;
    const float* sp_l = spk + l * HW;
    for (int idx = tid; idx < NSTG; idx += 128) {
        const int r    = idx / NSLOT;
        const int slot = idx - r * NSLOT;
        const int gy = gy0 + r;
        const int gx = gx0 + 4 * slot;
        float4 v = make_float4(0.f, 0.f, 0.f, 0.f);
        if ((unsigned)gy < (unsigned)H) {
            const float* src = sp_l + gy * W;
            if (gx >= 0 && gx + 3 < W) {
                v = *(const float4*)(src + gx);       // 16B aligned
            } else {
                float t0 = 0.f, t1 = 0.f, t2 = 0.f, t3 = 0.f;
                if ((unsigned)(gx + 0) < (unsigned)W) t0 = src[gx + 0];
                if ((unsigned)(gx + 1) < (unsigned)W) t1 = src[gx + 1];
                if ((unsigned)(gx + 2) < (unsigned)W) t2 = src[gx + 2];
                if ((unsigned)(gx + 3) < (unsigned)W) t3 = src[gx + 3];
                v = make_float4(t0, t1, t2, t3);
            }
        }
        *(float4*)&tile[r][4 * slot] = v;             // 16B aligned
    }
    __syncthreads();

    // ---- conv: 4 cols x 2 rows per thread, b128 window loads (round-7 body) ----
    float acc[2][4] = {{0.f,0.f,0.f,0.f},{0.f,0.f,0.f,0.f}};
    #pragma unroll
    for (int j = 0; j < 12; ++j) {                    // tile row = ty*2 + j
        const float* row = &tile[ty * 2 + j][0];
        alignas(16) float win[20];
        *(float4*)&win[0]  = *(const float4*)&row[4 * tx + 0];
        *(float4*)&win[4]  = *(const float4*)&row[4 * tx + 4];
        *(float4*)&win[8]  = *(const float4*)&row[4 * tx + 8];
        *(float4*)&win[12] = *(const float4*)&row[4 * tx + 12];
        win[16] = row[4 * tx + 16];
        #pragma unroll
        for (int k = 0; k < 2; ++k) {
            const int dy = j - k;
            if (dy < 0 || dy > 10) continue;          // compile-time pruned
            #pragma unroll
            for (int dx = XLO[dy]; dx <= XHI[dy]; ++dx) {
                const float wv = wt.w[WOFF[dy] + dx - XLO[dy]];  // SGPR
                #pragma unroll
                for (int c = 0; c < 4; ++c)
                    acc[k][c] += wv * win[3 + c + dx];  // window base offset 3
            }
        }
    }

    // ---- tail: axonal + LIF + threshold, all float4, per output row ----
    const int ox = bx * TWB + 4 * tx;
    #pragma unroll
    for (int k = 0; k < 2; ++k) {
        const int oy   = by * TH + ty * 2 + k;
        const int pidx = oy * W + ox;
        const int gidx = l * HW + pidx;

        const int4   rf4 = *(const int4*)  (refr + gidx);
        const float4 e4  = *(const float4*)(ext  + gidx);
        const float4 m4  = *(const float4*)(mem  + gidx);

        float ax0 = 0.f, ax1 = 0.f, ax2 = 0.f, ax3 = 0.f;
        #pragma unroll
        for (int c = 0; c < C; ++c) {
            if (CDST[c] != l) continue;               // block-uniform
            const float4 s4 = *(const float4*)(spk + CSRC[c] * HW + pidx);
            const float4 w4 = *(const float4*)(iw  + c       * HW + pidx);
            ax0 += s4.x * w4.x; ax1 += s4.y * w4.y;
            ax2 += s4.z * w4.z; ax3 += s4.w * w4.w;
        }
        const float ee[4] = {e4.x, e4.y, e4.z, e4.w};
        const float mm[4] = {m4.x, m4.y, m4.z, m4.w};
        const int   rr[4] = {rf4.x, rf4.y, rf4.z, rf4.w};
        const float aa[4] = {ax0, ax1, ax2, ax3};
        float res[4];
        #pragma unroll
        for (int c = 0; c < 4; ++c) {
            const float v = 0.9f * mm[c] + (ee[c] + acc[k][c] + aa[c]);
            res[c] = (rr[c] == 0 && v > 0.f) ? 1.f : 0.f;
            if (rr[c] == 0 && __builtin_expect(fabsf(v) < 1e-3f, 0)) {
                const unsigned idx = atomicAdd(wslist, 1u);
                if (idx < cap) wslist[1 + idx] = (unsigned)(gidx + c);
            }
        }
        *(float4*)(out + gidx) = make_float4(res[0], res[1], res[2], res[3]);
    }
}

// ---------------- fixup kernel: exact f64 recompute of flagged pixels ----------------
__global__ __launch_bounds__(256)
void snn_fixup(const float* __restrict__ ext,
               const float* __restrict__ spk,
               const float* __restrict__ mem,
               const float* __restrict__ iw,
               const float* __restrict__ lk,
               float* __restrict__ out,
               const unsigned* __restrict__ wslist,
               unsigned cap)
{
    const unsigned n = min(wslist[0], cap);
    for (unsigned i = blockIdx.x * blockDim.x + threadIdx.x; i < n;
         i += gridDim.x * blockDim.x) {
        const unsigned gidx = wslist[1 + i];
        const int l    = gidx / HW;
        const int pidx = gidx - l * HW;
        const int oy   = pidx / W;
        const int ox   = pidx - oy * W;

        const float* sp = spk + l * HW;
        double conv = 0.0;
        for (int dy = 0; dy < 11; ++dy) {
            const int yy = oy + dy - 5;
            if ((unsigned)yy >= (unsigned)H) continue;
            for (int dx = 0; dx < 11; ++dx) {
                const int xx = ox + dx - 5;
                if ((unsigned)xx >= (unsigned)W) continue;
                conv += (double)lk[dy * 11 + dx] * (double)sp[yy * W + xx];
            }
        }
        double ax = 0.0;
        #pragma unroll
        for (int c = 0; c < C; ++c)
            if (CDST[c] == l)
                ax += (double)spk[CSRC[c] * HW + pidx] * (double)iw[c * HW + pidx];
        const double tot = ((double)ext[gidx] + conv) + ax;
        const double vd  = 0.9 * (double)mem[gidx] + tot;
        out[gidx] = (vd > 0.0) ? 1.f : 0.f;
    }
}

} // namespace

extern "C" void kernel_launch(void* const* d_in, const int* in_sizes, int n_in,
                              void* d_out, int out_size, void* d_ws, size_t ws_size,
                              hipStream_t stream) {
    const float* ext  = (const float*)d_in[0];
    const float* spk  = (const float*)d_in[1];
    const float* mem  = (const float*)d_in[2];
    const float* iw   = (const float*)d_in[3];
    const float* lk   = (const float*)d_in[4];
    const int*   refr = (const int*)  d_in[5];
    float* o = (float*)d_out;

    // host-side f64 weight computation, mirroring numpy
    Weights wt;
    for (int dy = 0; dy < 11; ++dy) {
        for (int dx = XLO[dy]; dx <= XHI[dy]; ++dx) {
            const double ddy = dy - 5, ddx = dx - 5;
            const double dist = std::sqrt(ddy * ddy + ddx * ddx);
            double w = std::exp(-dist / 2.0);
            if (dist > 5.0) w = 0.0;
            if (dy == 5 && dx == 5) w = 0.0;
            wt.w[WOFF[dy] + dx - XLO[dy]] = (float)w;
        }
    }

    dim3 grid(W / TWB, H / TH, L);   // (12, 192, 8)
    dim3 block(32, 4, 1);

    unsigned* wsl = (unsigned*)d_ws;
    size_t cap64 = ws_size / 4 - 1;
    const unsigned cap = (unsigned)(cap64 > 0x7FFFFFFFu ? 0x7FFFFFFFu : cap64);
    hipMemsetAsync(d_ws, 0, 4, stream);   // zero the counter (graph-safe)
    hipLaunchKernelGGL(snn_fast, grid, block, 0, stream,
                       ext, spk, mem, iw, refr, o, wsl, cap, wt);
    hipLaunchKernelGGL(snn_fixup, dim3(64), dim3(256), 0, stream,
                       ext, spk, mem, iw, lk, o, wsl, cap);
}

// Round 12
// 183.890 us; speedup vs baseline: 4.6693x; 1.0528x over previous
//
#include <hip/hip_runtime.h>
#include <cmath>

namespace {

constexpr int L = 8, H = 1536, W = 1536, HW = H * W, C = 12;
constexpr int TWB = 128, TH = 16;          // block output tile 128x16
constexpr int LH = TH + 10;                // 26 tile rows
constexpr int LPAD = 8;                    // left halo padded to 8 for 16B alignment
constexpr int LCOLS = 148;                 // 36 float4 data slots (144) + 4 pad

// nonzero-tap extents of the 11x11 disc (dist<=5)
__device__ __host__ constexpr int XLO[11]  = {5, 2, 1, 1, 1, 0, 1, 1, 1, 2, 5};
__device__ __host__ constexpr int XHI[11]  = {5, 8, 9, 9, 9,10, 9, 9, 9, 8, 5};
__device__ __host__ constexpr int WOFF[11] = {0, 1, 8,17,26,35,46,55,64,73,80}; // 81 total

// fixed topology from the reference (_PAIRS)
__device__ constexpr int CSRC[C] = {0,1,2,3,4,5,6,0,2,4,7,3};
__device__ constexpr int CDST[C] = {1,2,3,4,5,6,7,2,4,6,0,5};

struct Weights { float w[81]; };

// ---------------- fast kernel: accumulator seeded BEFORE the conv ----------------
__global__ __launch_bounds__(256)   // NO min-waves pin (rounds 2/6/9 lesson)
void snn_fast(const float* __restrict__ ext,
              const float* __restrict__ spk,
              const float* __restrict__ mem,
              const float* __restrict__ iw,
              const int*   __restrict__ refr,
              float* __restrict__ out,
              unsigned*    wslist,          // [0]=count, [1..cap]=gidx list
              unsigned     cap,
              const Weights wt)
{
    __shared__ float tile[LH][LCOLS];

    const int tx = threadIdx.x;          // 0..31
    const int ty = threadIdx.y;          // 0..7
    const int tid = ty * 32 + tx;
    const int bx = blockIdx.x, by = blockIdx.y, l = blockIdx.z;

    // ---- stage spike tile: aligned float4 path, edge fallback ----
    const int gx0 = bx * TWB - LPAD;     // global x of tile col 0 (16B aligned)
    const int gy0 = by * TH - 5;
    const float* sp_l = spk + l * HW;
    for (int idx = tid; idx < LH * 36; idx += 256) {
        const int r    = idx / 36;
        const int slot = idx - r * 36;
        const int gy = gy0 + r;
        const int gx = gx0 + 4 * slot;
        float4 v = make_float4(0.f, 0.f, 0.f, 0.f);
        if ((unsigned)gy < (unsigned)H) {
            const float* src = sp_l + gy * W;
            if (gx >= 0 && gx + 3 < W) {
                v = *(const float4*)(src + gx);       // 16B aligned
            } else {
                float t0 = 0.f, t1 = 0.f, t2 = 0.f, t3 = 0.f;
                if ((unsigned)(gx + 0) < (unsigned)W) t0 = src[gx + 0];
                if ((unsigned)(gx + 1) < (unsigned)W) t1 = src[gx + 1];
                if ((unsigned)(gx + 2) < (unsigned)W) t2 = src[gx + 2];
                if ((unsigned)(gx + 3) < (unsigned)W) t3 = src[gx + 3];
                v = make_float4(t0, t1, t2, t3);
            }
        }
        *(float4*)&tile[r][4 * slot] = v;             // 16B aligned
    }
    __syncthreads();

    const int ox    = bx * TWB + 4 * tx;
    const int oy0   = by * TH + ty * 2;
    const int pidx0 = oy0 * W + ox;
    const int gidx0 = l * HW + pidx0;

    // ---- seed phase: fold ext + axonal into acc, refr -> 1-reg mask, keep m ----
    float acc[2][4];
    float mv [2][4];
    unsigned mask = 0;
    #pragma unroll
    for (int k = 0; k < 2; ++k) {
        const int gidx = gidx0 + k * W;
        const int4   rf4 = *(const int4*)  (refr + gidx);
        const float4 e4  = *(const float4*)(ext  + gidx);
        const float4 m4  = *(const float4*)(mem  + gidx);
        acc[k][0] = e4.x; acc[k][1] = e4.y; acc[k][2] = e4.z; acc[k][3] = e4.w;
        mv [k][0] = m4.x; mv [k][1] = m4.y; mv [k][2] = m4.z; mv [k][3] = m4.w;
        mask |= (rf4.x == 0 ? 1u : 0u) << (k * 4 + 0);
        mask |= (rf4.y == 0 ? 1u : 0u) << (k * 4 + 1);
        mask |= (rf4.z == 0 ? 1u : 0u) << (k * 4 + 2);
        mask |= (rf4.w == 0 ? 1u : 0u) << (k * 4 + 3);
        #pragma unroll
        for (int c = 0; c < C; ++c) {
            if (CDST[c] != l) continue;               // block-uniform
            const float4 s4 = *(const float4*)(spk + CSRC[c] * HW + gidx - l * HW);
            const float4 w4 = *(const float4*)(iw  + c       * HW + gidx - l * HW);
            acc[k][0] += s4.x * w4.x; acc[k][1] += s4.y * w4.y;
            acc[k][2] += s4.z * w4.z; acc[k][3] += s4.w * w4.w;
        }
    }

    // ---- conv: 4 cols x 2 rows per thread, b128 window loads (round-7 body) ----
    #pragma unroll
    for (int j = 0; j < 12; ++j) {                    // tile row = ty*2 + j
        const float* row = &tile[ty * 2 + j][0];
        alignas(16) float win[20];
        *(float4*)&win[0]  = *(const float4*)&row[4 * tx + 0];
        *(float4*)&win[4]  = *(const float4*)&row[4 * tx + 4];
        *(float4*)&win[8]  = *(const float4*)&row[4 * tx + 8];
        *(float4*)&win[12] = *(const float4*)&row[4 * tx + 12];
        win[16] = row[4 * tx + 16];
        #pragma unroll
        for (int k = 0; k < 2; ++k) {
            const int dy = j - k;
            if (dy < 0 || dy > 10) continue;          // compile-time pruned
            #pragma unroll
            for (int dx = XLO[dy]; dx <= XHI[dy]; ++dx) {
                const float wv = wt.w[WOFF[dy] + dx - XLO[dy]];  // SGPR
                #pragma unroll
                for (int c = 0; c < 4; ++c)
                    acc[k][c] += wv * win[3 + c + dx];  // window base offset 3
            }
        }
    }

    // ---- tail: pure arithmetic, no global loads ----
    #pragma unroll
    for (int k = 0; k < 2; ++k) {
        const int gidx = gidx0 + k * W;
        float res[4];
        #pragma unroll
        for (int c = 0; c < 4; ++c) {
            const bool act = (mask >> (k * 4 + c)) & 1u;
            const float v = fmaf(0.9f, mv[k][c], acc[k][c]);
            res[c] = (act && v > 0.f) ? 1.f : 0.f;
            if (act && __builtin_expect(fabsf(v) < 1e-3f, 0)) {
                const unsigned idx = atomicAdd(wslist, 1u);
                if (idx < cap) wslist[1 + idx] = (unsigned)(gidx + c);
            }
        }
        *(float4*)(out + gidx) = make_float4(res[0], res[1], res[2], res[3]);
    }
}

// ---------------- fixup kernel: exact f64 recompute of flagged pixels ----------------
__global__ __launch_bounds__(256)
void snn_fixup(const float* __restrict__ ext,
               const float* __restrict__ spk,
               const float* __restrict__ mem,
               const float* __restrict__ iw,
               const float* __restrict__ lk,
               float* __restrict__ out,
               const unsigned* __restrict__ wslist,
               unsigned cap)
{
    const unsigned n = min(wslist[0], cap);
    for (unsigned i = blockIdx.x * blockDim.x + threadIdx.x; i < n;
         i += gridDim.x * blockDim.x) {
        const unsigned gidx = wslist[1 + i];
        const int l    = gidx / HW;
        const int pidx = gidx - l * HW;
        const int oy   = pidx / W;
        const int ox   = pidx - oy * W;

        const float* sp = spk + l * HW;
        double conv = 0.0;
        for (int dy = 0; dy < 11; ++dy) {
            const int yy = oy + dy - 5;
            if ((unsigned)yy >= (unsigned)H) continue;
            for (int dx = 0; dx < 11; ++dx) {
                const int xx = ox + dx - 5;
                if ((unsigned)xx >= (unsigned)W) continue;
                conv += (double)lk[dy * 11 + dx] * (double)sp[yy * W + xx];
            }
        }
        double ax = 0.0;
        #pragma unroll
        for (int c = 0; c < C; ++c)
            if (CDST[c] == l)
                ax += (double)spk[CSRC[c] * HW + pidx] * (double)iw[c * HW + pidx];
        const double tot = ((double)ext[gidx] + conv) + ax;
        const double vd  = 0.9 * (double)mem[gidx] + tot;
        out[gidx] = (vd > 0.0) ? 1.f : 0.f;
    }
}

} // namespace

extern "C" void kernel_launch(void* const* d_in, const int* in_sizes, int n_in,
                              void* d_out, int out_size, void* d_ws, size_t ws_size,
                              hipStream_t stream) {
    const float* ext  = (const float*)d_in[0];
    const float* spk  = (const float*)d_in[1];
    const float* mem  = (const float*)d_in[2];
    const float* iw   = (const float*)d_in[3];
    const float* lk   = (const float*)d_in[4];
    const int*   refr = (const int*)  d_in[5];
    float* o = (float*)d_out;

    // host-side f64 weight computation, mirroring numpy
    Weights wt;
    for (int dy = 0; dy < 11; ++dy) {
        for (int dx = XLO[dy]; dx <= XHI[dy]; ++dx) {
            const double ddy = dy - 5, ddx = dx - 5;
            const double dist = std::sqrt(ddy * ddy + ddx * ddx);
            double w = std::exp(-dist / 2.0);
            if (dist > 5.0) w = 0.0;
            if (dy == 5 && dx == 5) w = 0.0;
            wt.w[WOFF[dy] + dx - XLO[dy]] = (float)w;
        }
    }

    dim3 grid(W / TWB, H / TH, L);   // (12, 96, 8)
    dim3 block(32, 8, 1);

    unsigned* wsl = (unsigned*)d_ws;
    size_t cap64 = ws_size / 4 - 1;
    const unsigned cap = (unsigned)(cap64 > 0x7FFFFFFFu ? 0x7FFFFFFFu : cap64);
    hipMemsetAsync(d_ws, 0, 4, stream);   // zero the counter (graph-safe)
    hipLaunchKernelGGL(snn_fast, grid, block, 0, stream,
                       ext, spk, mem, iw, refr, o, wsl, cap, wt);
    hipLaunchKernelGGL(snn_fixup, dim3(64), dim3(256), 0, stream,
                       ext, spk, mem, iw, lk, o, wsl, cap);
}